// Round 5
// baseline (243.135 us; speedup 1.0000x reference)
//
#include <hip/hip_runtime.h>
#include <hip/hip_bf16.h>

// SRU layer: LN -> bf16 MFMA GEMM (256^2, 8-phase, B-from-global fragments) -> chunked scan.
// L=2048, B=8, D=1024, M=16384, K=1024, N=3072.

typedef unsigned short u16;
typedef __bf16 bf16x8 __attribute__((ext_vector_type(8)));
typedef float f32x4 __attribute__((ext_vector_type(4)));

#define L_DIM 2048
#define B_DIM 8
#define D_DIM 1024
#define M_DIM (L_DIM * B_DIM)   // 16384
#define K_DIM D_DIM             // 1024
#define N_DIM (3 * D_DIM)       // 3072
#define NCH 32
#define CLEN (L_DIM / NCH)      // 64
#define NT (K_DIM / 64)         // 16 K-tiles

// LDS: A double-buffer 2x32KB + 16KB dummy = 80KB
#define LDS_DUMMY 65536
#define LDS_TOTAL 81920

__device__ __forceinline__ float bf2f(u16 h) {
    unsigned int u = ((unsigned int)h) << 16;
    float f;
    __builtin_memcpy(&f, &u, 4);
    return f;
}

__device__ __forceinline__ u16 f2bf(float f) {
    unsigned int u;
    __builtin_memcpy(&u, &f, 4);
    u = u + 0x7fff + ((u >> 16) & 1);   // RNE
    return (u16)(u >> 16);
}

__device__ __forceinline__ void async16(void* lds, const void* g) {
    __builtin_amdgcn_global_load_lds(
        (const __attribute__((address_space(1))) void*)g,
        (__attribute__((address_space(3))) void*)lds, 16, 0, 0);
}

// ---------------- LayerNorm (saves per-row mu/rs for scan3) ----------------
__global__ __launch_bounds__(256) void ln_kernel(const float* __restrict__ x,
                                                 const float* __restrict__ gamma,
                                                 const float* __restrict__ beta,
                                                 u16* __restrict__ xn,
                                                 float2* __restrict__ mrs) {
    int row = blockIdx.x;
    int tid = threadIdx.x;
    const float4* xr = (const float4*)(x + (size_t)row * D_DIM);
    float4 v = xr[tid];
    float s = v.x + v.y + v.z + v.w;
    float q = v.x * v.x + v.y * v.y + v.z * v.z + v.w * v.w;
    #pragma unroll
    for (int off = 32; off; off >>= 1) {
        s += __shfl_down(s, off);
        q += __shfl_down(q, off);
    }
    __shared__ float ss[4], qq[4];
    int lane = tid & 63, wv = tid >> 6;
    if (lane == 0) { ss[wv] = s; qq[wv] = q; }
    __syncthreads();
    s = ss[0] + ss[1] + ss[2] + ss[3];
    q = qq[0] + qq[1] + qq[2] + qq[3];
    float mu = s * (1.0f / D_DIM);
    float var = q * (1.0f / D_DIM) - mu * mu;
    float rs = rsqrtf(var + 1e-5f);
    if (tid == 0) mrs[row] = make_float2(mu, rs);
    float4 g = ((const float4*)gamma)[tid];
    float4 bt = ((const float4*)beta)[tid];
    ushort4 o;
    o.x = f2bf((v.x - mu) * rs * g.x + bt.x);
    o.y = f2bf((v.y - mu) * rs * g.y + bt.y);
    o.z = f2bf((v.z - mu) * rs * g.z + bt.z);
    o.w = f2bf((v.w - mu) * rs * g.w + bt.w);
    ((ushort4*)(xn + (size_t)row * D_DIM))[tid] = o;
}

// ---------------- W -> fragment-contiguous bf16 layout ----------------
// Wf[n16][k32][lane][8]: lane l, elem e = W[k32*32 + (l>>4)*8 + e][n16*16 + (l&15)]
// One wave builds one 1KB fragment; a wave's MFMA B-load is then a single
// coalesced dwordx4 at frag_base + lane*16.
__global__ __launch_bounds__(256) void wtf_kernel(const float* __restrict__ W,
                                                  u16* __restrict__ Wf) {
    int wv = threadIdx.x >> 6, lane = threadIdx.x & 63;
    int n16 = blockIdx.x * 4 + wv;          // 0..191
    int k32 = blockIdx.y;                   // 0..31
    int lm = lane & 15, lg = lane >> 4;
    int col = n16 * 16 + lm;
    u16 o[8];
    #pragma unroll
    for (int e = 0; e < 8; ++e) {
        int row = k32 * 32 + lg * 8 + e;
        o[e] = f2bf(W[(size_t)row * N_DIM + col]);
    }
    u16* dst = Wf + (((size_t)n16 * 32 + k32) << 9) + (lane << 3);
    *(ulonglong2*)dst = *(ulonglong2*)o;
}

// ---------------- GEMM: 256x256 tile, BK=64, 8 waves, A-in-LDS, B-from-global ----
// Per tile t (4 phases): a: {load bv_kk0 (4 dwordx4), stage A(t+1)h0, ds av(mf0-3,k0)}
//                        b: {load bv_kk1, stage A(t+1)h1, ds av(mf0-3,k1)}
//                        g: {ds av(mf4-7,k0)}   d: {ds av(mf4-7,k1); vmcnt(0)}
// Correctness rests only on the end-of-tile vmcnt(0) (A(t+1) fully landed) +
// compiler-inserted waits on bv registers; all other waits are perf-only.
__device__ __forceinline__ void stage_halfA(const u16* __restrict__ A, int m0,
                                            int t, int h, char* lds,
                                            int tid, int wave) {
    int tc = (t < NT) ? t : 0;
    char* dst0 = (t < NT) ? (lds + (t & 1) * 32768 + h * 16384)
                          : (lds + LDS_DUMMY);
    int k0 = tc * 64;
    #pragma unroll
    for (int s = 0; s < 2; ++s) {
        int c = s * 512 + tid;
        int row = h * 128 + (c >> 3);
        int cc = (c & 7) ^ (row & 7);   // pre-swizzled global source (rule 21)
        async16(dst0 + s * 8192 + wave * 1024,
                A + (size_t)(m0 + row) * K_DIM + k0 + cc * 8);
    }
}

__global__ __launch_bounds__(512, 2) void gemm_kernel(const u16* __restrict__ A,
                                                      const u16* __restrict__ Wf,
                                                      const float* __restrict__ bias,
                                                      u16* __restrict__ uo,
                                                      u16* __restrict__ fo,
                                                      u16* __restrict__ ro) {
    extern __shared__ char lds[];
    const int tid = threadIdx.x;
    const int wave = tid >> 6, lane = tid & 63;
    const int lm = lane & 15, lg = lane >> 4;
    const int wm = wave >> 2, wn = wave & 3;   // 2M x 4N waves
    const int m0 = blockIdx.x * 256;           // natural grid (R2 locality)
    const int n0 = blockIdx.y * 256;
    const int n16w = (n0 >> 4) + wn * 4;

    f32x4 acc[8][4] = {};
    bf16x8 av[4], bv0[4], bv1[4];

#define LDA(bb, mf0, kk)                                                        \
    do { _Pragma("unroll")                                                      \
        for (int q = 0; q < 4; ++q) {                                           \
            int row_ = wm * 128 + ((mf0) + q) * 16 + lm;                        \
            av[q] = *(const bf16x8*)(lds + (bb) * 32768 + row_ * 128            \
                     + (((((kk) << 2) | lg) ^ (lm & 7)) << 4));                 \
        } } while (0)

#define LDBG(dst, t, kk)                                                        \
    do { _Pragma("unroll")                                                      \
        for (int nf = 0; nf < 4; ++nf)                                          \
            dst[nf] = *(const bf16x8*)(Wf + ((size_t)((n16w + nf) * 32          \
                      + (t) * 2 + (kk)) << 9) + (lane << 3));                   \
    } while (0)

#define MFMA16(r0, bfr)                                                         \
    do { _Pragma("unroll")                                                      \
        for (int q = 0; q < 4; ++q)                                             \
            _Pragma("unroll")                                                   \
            for (int nf = 0; nf < 4; ++nf)                                      \
                acc[(r0) + q][nf] = __builtin_amdgcn_mfma_f32_16x16x32_bf16(    \
                    av[q], bfr[nf], acc[(r0) + q][nf], 0, 0, 0);                \
    } while (0)

#define PH_SYNC()                                                               \
    do { __builtin_amdgcn_s_barrier();                                          \
         asm volatile("s_waitcnt lgkmcnt(0)");                                  \
         __builtin_amdgcn_sched_barrier(0); } while (0)

#define TILE_BODY(t, bb)                                                        \
    do {                                                                        \
        /* phase a */                                                           \
        LDBG(bv0, (t), 0);                                                      \
        stage_halfA(A, m0, (t) + 1, 0, lds, tid, wave);                         \
        LDA(bb, 0, 0);                                                          \
        PH_SYNC();                                                              \
        __builtin_amdgcn_s_setprio(1);  MFMA16(0, bv0);                         \
        __builtin_amdgcn_s_setprio(0);  __builtin_amdgcn_s_barrier();           \
        /* phase b */                                                           \
        LDBG(bv1, (t), 1);                                                      \
        stage_halfA(A, m0, (t) + 1, 1, lds, tid, wave);                         \
        LDA(bb, 0, 1);                                                          \
        PH_SYNC();                                                              \
        __builtin_amdgcn_s_setprio(1);  MFMA16(0, bv1);                         \
        __builtin_amdgcn_s_setprio(0);  __builtin_amdgcn_s_barrier();           \
        /* phase g */                                                           \
        LDA(bb, 4, 0);                                                          \
        PH_SYNC();                                                              \
        __builtin_amdgcn_s_setprio(1);  MFMA16(4, bv0);                         \
        __builtin_amdgcn_s_setprio(0);  __builtin_amdgcn_s_barrier();           \
        /* phase d */                                                           \
        LDA(bb, 4, 1);                                                          \
        PH_SYNC();                                                              \
        __builtin_amdgcn_s_setprio(1);  MFMA16(4, bv1);                         \
        __builtin_amdgcn_s_setprio(0);                                          \
        asm volatile("s_waitcnt vmcnt(0)" ::: "memory");                        \
        __builtin_amdgcn_s_barrier();                                           \
    } while (0)

    // prologue: stage A(0) only; drain; barrier
    stage_halfA(A, m0, 0, 0, lds, tid, wave);
    stage_halfA(A, m0, 0, 1, lds, tid, wave);
    asm volatile("s_waitcnt vmcnt(0)" ::: "memory");
    __builtin_amdgcn_s_barrier();

    for (int t = 0; t < NT; t += 2) {
        TILE_BODY(t, 0);
        TILE_BODY(t + 1, 1);
    }

    // epilogue: bias + sigmoid (f/r), bf16 store
    int seg = n0 >> 10;   // block-uniform (256 | 1024)
    u16* outp = (seg == 0) ? uo : ((seg == 1) ? fo : ro);
    #pragma unroll
    for (int nf = 0; nf < 4; ++nf) {
        int col = n0 + wn * 64 + nf * 16 + lm;
        int cm = col & 1023;
        float bb2 = bias[col];
        #pragma unroll
        for (int mf = 0; mf < 8; ++mf) {
            #pragma unroll
            for (int j = 0; j < 4; ++j) {
                int row = m0 + wm * 128 + mf * 16 + lg * 4 + j;
                float val = acc[mf][nf][j] + bb2;
                if (seg != 0) val = 1.0f / (1.0f + __expf(-val));
                outp[(size_t)row * D_DIM + cm] = f2bf(val);
            }
        }
    }
#undef LDA
#undef LDBG
#undef MFMA16
#undef PH_SYNC
#undef TILE_BODY
}

// ---------------- Scan phase 1 ----------------
__global__ __launch_bounds__(256) void scan1_kernel(const u16* __restrict__ fg,
                                                    const u16* __restrict__ u,
                                                    float* __restrict__ Aa,
                                                    float* __restrict__ Ss) {
    int ch = blockIdx.x;
    int bd = (blockIdx.y * 256 + threadIdx.x) * 2;
    int b = bd >> 10, d = bd & 1023;
    float a0 = 1.0f, a1 = 1.0f, s0 = 0.0f, s1 = 0.0f;
    for (int t = ch * CLEN; t < ch * CLEN + CLEN; ++t) {
        size_t idx = ((size_t)(t * B_DIM + b) << 10) + d;
        ushort2 f2 = *(const ushort2*)(fg + idx);
        ushort2 u2 = *(const ushort2*)(u + idx);
        float f0 = bf2f(f2.x), f1 = bf2f(f2.y);
        float v0 = bf2f(u2.x), v1 = bf2f(u2.y);
        s0 = f0 * s0 + (1.0f - f0) * v0;
        s1 = f1 * s1 + (1.0f - f1) * v1;
        a0 *= f0;
        a1 *= f1;
    }
    int o = ch * 8192 + bd;
    *(float2*)(Aa + o) = make_float2(a0, a1);
    *(float2*)(Ss + o) = make_float2(s0, s1);
}

// ---------------- Scan phase 2 ----------------
__global__ __launch_bounds__(256) void scan2_kernel(const float* __restrict__ Aa,
                                                    const float* __restrict__ Ss,
                                                    const float* __restrict__ c0,
                                                    float* __restrict__ cs,
                                                    float* __restrict__ lastc) {
    int bd = blockIdx.x * 256 + threadIdx.x;
    float c = c0[bd];
    #pragma unroll 4
    for (int ch = 0; ch < NCH; ++ch) {
        cs[ch * 8192 + bd] = c;
        c = Aa[ch * 8192 + bd] * c + Ss[ch * 8192 + bd];
    }
    lastc[bd] = c;
}

// ---------------- Scan phase 3: replay + recompute x_norm from x ----------------
__global__ __launch_bounds__(256) void scan3_kernel(const float* __restrict__ cs,
                                                    const u16* __restrict__ fg,
                                                    const u16* __restrict__ u,
                                                    const u16* __restrict__ rg,
                                                    const float2* __restrict__ mrs,
                                                    const float* __restrict__ gamma,
                                                    const float* __restrict__ beta,
                                                    const float* __restrict__ x,
                                                    float* __restrict__ out) {
    int ch = blockIdx.x;
    int bd = (blockIdx.y * 256 + threadIdx.x) * 2;
    int b = bd >> 10, d = bd & 1023;
    float2 gm = *(const float2*)(gamma + d);
    float2 bt = *(const float2*)(beta + d);
    float c0v = cs[ch * 8192 + bd];
    float c1v = cs[ch * 8192 + bd + 1];
    for (int t = ch * CLEN; t < ch * CLEN + CLEN; ++t) {
        size_t idx = ((size_t)(t * B_DIM + b) << 10) + d;
        ushort2 f2 = *(const ushort2*)(fg + idx);
        ushort2 u2 = *(const ushort2*)(u + idx);
        ushort2 r2 = *(const ushort2*)(rg + idx);
        float2 x2 = *(const float2*)(x + idx);
        float2 mr = mrs[t * B_DIM + b];
        float f0 = bf2f(f2.x), f1 = bf2f(f2.y);
        float v0 = bf2f(u2.x), v1 = bf2f(u2.y);
        float r0 = bf2f(r2.x), r1 = bf2f(r2.y);
        float n0 = (x2.x - mr.x) * mr.y * gm.x + bt.x;
        float n1 = (x2.y - mr.x) * mr.y * gm.y + bt.y;
        c0v = f0 * c0v + (1.0f - f0) * v0;
        c1v = f1 * c1v + (1.0f - f1) * v1;
        float h0 = r0 * tanhf(c0v) + (1.0f - r0) * n0;
        float h1 = r1 * tanhf(c1v) + (1.0f - r1) * n1;
        *(float2*)(out + idx) = make_float2(x2.x + h0, x2.y + h1);
    }
}

extern "C" void kernel_launch(void* const* d_in, const int* in_sizes, int n_in,
                              void* d_out, int out_size, void* d_ws, size_t ws_size,
                              hipStream_t stream) {
    const float* x     = (const float*)d_in[0];
    const float* c0    = (const float*)d_in[1];
    const float* W     = (const float*)d_in[2];
    const float* b     = (const float*)d_in[3];
    const float* gamma = (const float*)d_in[4];
    const float* beta  = (const float*)d_in[5];
    float* out = (float*)d_out;
    float* lastc = out + (size_t)M_DIM * D_DIM;

    char* w = (char*)d_ws;
    u16* xn = (u16*)w;  w += (size_t)M_DIM * D_DIM * 2;
    u16* Wf = (u16*)w;  w += (size_t)N_DIM * K_DIM * 2;
    u16* ug = (u16*)w;  w += (size_t)M_DIM * D_DIM * 2;
    u16* fg = (u16*)w;  w += (size_t)M_DIM * D_DIM * 2;
    u16* rg = (u16*)w;  w += (size_t)M_DIM * D_DIM * 2;
    float* Aa = (float*)w; w += (size_t)NCH * 8192 * 4;
    float* Ss = (float*)w; w += (size_t)NCH * 8192 * 4;
    float* cs = (float*)w; w += (size_t)NCH * 8192 * 4;
    float2* mrs = (float2*)w; w += (size_t)M_DIM * 8;

    hipFuncSetAttribute(reinterpret_cast<const void*>(gemm_kernel),
                        hipFuncAttributeMaxDynamicSharedMemorySize, LDS_TOTAL);

    ln_kernel<<<M_DIM, 256, 0, stream>>>(x, gamma, beta, xn, mrs);
    wtf_kernel<<<dim3(N_DIM / 64, K_DIM / 32), 256, 0, stream>>>(W, Wf);
    gemm_kernel<<<dim3(M_DIM / 256, N_DIM / 256), 512, LDS_TOTAL, stream>>>(xn, Wf, b, ug, fg, rg);
    scan1_kernel<<<dim3(NCH, 16), 256, 0, stream>>>(fg, ug, Aa, Ss);
    scan2_kernel<<<32, 256, 0, stream>>>(Aa, Ss, c0, cs, lastc);
    scan3_kernel<<<dim3(NCH, 16), 256, 0, stream>>>(cs, fg, ug, rg, mrs, gamma, beta, x, out);
}

// Round 6
// 215.214 us; speedup vs baseline: 1.1297x; 1.1297x over previous
//
#include <hip/hip_runtime.h>
#include <hip/hip_bf16.h>

// SRU layer: LN -> bf16 MFMA GEMM (256^2 8-phase, balanced reads) -> chunked scan.
// L=2048, B=8, D=1024, M=16384, K=1024, N=3072.

typedef unsigned short u16;
typedef __bf16 bf16x8 __attribute__((ext_vector_type(8)));
typedef float f32x4 __attribute__((ext_vector_type(4)));

#define L_DIM 2048
#define B_DIM 8
#define D_DIM 1024
#define M_DIM (L_DIM * B_DIM)   // 16384
#define K_DIM D_DIM             // 1024
#define N_DIM (3 * D_DIM)       // 3072
#define NCH 32
#define CLEN (L_DIM / NCH)      // 64
#define NT (K_DIM / 64)         // 16 K-tiles

#define LDS_B 65536
#define LDS_DUMMY 131072
#define LDS_TOTAL 147456

__device__ __forceinline__ float bf2f(u16 h) {
    unsigned int u = ((unsigned int)h) << 16;
    float f;
    __builtin_memcpy(&f, &u, 4);
    return f;
}

__device__ __forceinline__ u16 f2bf(float f) {
    unsigned int u;
    __builtin_memcpy(&u, &f, 4);
    u = u + 0x7fff + ((u >> 16) & 1);   // RNE
    return (u16)(u >> 16);
}

__device__ __forceinline__ void async16(void* lds, const void* g) {
    __builtin_amdgcn_global_load_lds(
        (const __attribute__((address_space(1))) void*)g,
        (__attribute__((address_space(3))) void*)lds, 16, 0, 0);
}

// ---------------- LayerNorm (saves per-row mu/rs for scan3) ----------------
__global__ __launch_bounds__(256) void ln_kernel(const float* __restrict__ x,
                                                 const float* __restrict__ gamma,
                                                 const float* __restrict__ beta,
                                                 u16* __restrict__ xn,
                                                 float2* __restrict__ mrs) {
    int row = blockIdx.x;
    int tid = threadIdx.x;
    const float4* xr = (const float4*)(x + (size_t)row * D_DIM);
    float4 v = xr[tid];
    float s = v.x + v.y + v.z + v.w;
    float q = v.x * v.x + v.y * v.y + v.z * v.z + v.w * v.w;
    #pragma unroll
    for (int off = 32; off; off >>= 1) {
        s += __shfl_down(s, off);
        q += __shfl_down(q, off);
    }
    __shared__ float ss[4], qq[4];
    int lane = tid & 63, wv = tid >> 6;
    if (lane == 0) { ss[wv] = s; qq[wv] = q; }
    __syncthreads();
    s = ss[0] + ss[1] + ss[2] + ss[3];
    q = qq[0] + qq[1] + qq[2] + qq[3];
    float mu = s * (1.0f / D_DIM);
    float var = q * (1.0f / D_DIM) - mu * mu;
    float rs = rsqrtf(var + 1e-5f);
    if (tid == 0) mrs[row] = make_float2(mu, rs);
    float4 g = ((const float4*)gamma)[tid];
    float4 bt = ((const float4*)beta)[tid];
    ushort4 o;
    o.x = f2bf((v.x - mu) * rs * g.x + bt.x);
    o.y = f2bf((v.y - mu) * rs * g.y + bt.y);
    o.z = f2bf((v.z - mu) * rs * g.z + bt.z);
    o.w = f2bf((v.w - mu) * rs * g.w + bt.w);
    ((ushort4*)(xn + (size_t)row * D_DIM))[tid] = o;
}

// ---------------- W transpose+convert: W[K][N] f32 -> Wt[N][K] bf16 ----------------
__global__ __launch_bounds__(256) void wt_kernel(const float* __restrict__ W,
                                                 u16* __restrict__ Wt) {
    __shared__ float t[64][65];
    int k0 = blockIdx.x * 64;
    int n0 = blockIdx.y * 64;
    int col = threadIdx.x & 63;
    int rg4 = threadIdx.x >> 6;
    #pragma unroll
    for (int j = 0; j < 16; ++j) {
        int r = rg4 * 16 + j;
        t[r][col] = W[(size_t)(k0 + r) * N_DIM + n0 + col];
    }
    __syncthreads();
    #pragma unroll
    for (int j = 0; j < 16; ++j) {
        int nr = rg4 * 16 + j;
        Wt[(size_t)(n0 + nr) * K_DIM + k0 + col] = f2bf(t[col][nr]);
    }
}

// ---------------- GEMM: 256x256, BK=64, 8 waves, 8-phase, BALANCED reads ----------------
// Per-phase ds_read bytes now 64/64/32/32 KB (was 96/32/64/0): each phase's burst
// fits the previous phase's MFMA execution shadow.
//   phase a: {av kk0 (4), bv0 (4)}  stage A(t+1)h0   MFMA(mf0-3, kk0)
//   phase b: {av kk1 (4), bv1 (4)}  stage A(t+1)h1   MFMA(mf0-3, kk1)
//   phase g: {aw kk0 (4)}           stage B(t+2)h0   MFMA(mf4-7, kk0)
//   phase d: {aw kk1 (4)}           stage B(t+2)h1   MFMA(mf4-7, kk1); vmcnt(4)
// Race proof as R2: B(t) reads complete at phase-b lgkmcnt+barrier before phase-g
// restages that buffer; A(t+1) staging targets the opposite buffer; vmcnt(4) at
// tile end guarantees tile t+1 fully landed.
__global__ __launch_bounds__(512, 2) void gemm_kernel(const u16* __restrict__ A,
                                                      const u16* __restrict__ Bt,
                                                      const float* __restrict__ bias,
                                                      u16* __restrict__ uo,
                                                      u16* __restrict__ fo,
                                                      u16* __restrict__ ro) {
    extern __shared__ char lds[];
    const int tid = threadIdx.x;
    const int wave = tid >> 6, lane = tid & 63;
    const int lm = lane & 15, lg = lane >> 4;
    const int wm = wave >> 2, wn = wave & 3;   // 2M x 4N waves
    const int m0 = blockIdx.x * 256;           // natural grid (keeps R2's L2 locality)
    const int n0 = blockIdx.y * 256;

    // --- precomputed ds_read bases (per-thread): addr = base + imm ---
    const int xk0 = ((0 | lg) ^ (lm & 7)) << 4;
    const int xk1 = ((4 | lg) ^ (lm & 7)) << 4;
    const char* pA0 = lds + (wm * 128 + lm) * 128 + xk0;
    const char* pA1 = lds + (wm * 128 + lm) * 128 + xk1;
    const char* pB0 = lds + LDS_B + (wn * 64 + lm) * 128 + xk0;
    const char* pB1 = lds + LDS_B + (wn * 64 + lm) * 128 + xk1;

    // --- precomputed staging addresses ---
    const int c1 = 512 + tid;
    const int r0 = tid >> 3, cc0 = (tid & 7) ^ (r0 & 7);   // pre-swizzled src (rule 21)
    const int r1 = c1 >> 3, cc1 = (c1 & 7) ^ (r1 & 7);
    const char* gA0 = (const char*)A + ((size_t)(m0 + r0) * K_DIM + cc0 * 8) * 2;
    const char* gA1 = (const char*)A + ((size_t)(m0 + r1) * K_DIM + cc1 * 8) * 2;
    const char* gB0 = (const char*)Bt + ((size_t)(n0 + r0) * K_DIM + cc0 * 8) * 2;
    const char* gB1 = (const char*)Bt + ((size_t)(n0 + r1) * K_DIM + cc1 * 8) * 2;
    char* dstW = lds + wave * 1024;

    f32x4 acc[8][4] = {};
    bf16x8 av[4], aw[4], bv0[4], bv1[4];

    auto stageA = [&](int t1, int h) {
        char* dst = (t1 < NT) ? (dstW + ((t1 & 1) << 15) + (h << 14))
                              : (lds + LDS_DUMMY + wave * 1024);
        int ko = ((t1 & 15) << 7) + (h << 18);
        async16(dst,        gA0 + ko);
        async16(dst + 8192, gA1 + ko);
    };
    auto stageB = [&](int t2, int h) {
        char* dst = (t2 < NT) ? (dstW + LDS_B + ((t2 & 1) << 15) + (h << 14))
                              : (lds + LDS_DUMMY + wave * 1024);
        int ko = ((t2 & 15) << 7) + (h << 18);
        async16(dst,        gB0 + ko);
        async16(dst + 8192, gB1 + ko);
    };

#define LDA(dst, pbase, bb, mf0)                                                \
    do { _Pragma("unroll")                                                      \
        for (int q = 0; q < 4; ++q)                                             \
            dst[q] = *(const bf16x8*)(pbase + (bb) * 32768 + ((mf0) + q) * 2048); \
    } while (0)

#define LDB(dst, pbase, bb)                                                     \
    do { _Pragma("unroll")                                                      \
        for (int nf = 0; nf < 4; ++nf)                                          \
            dst[nf] = *(const bf16x8*)(pbase + (bb) * 32768 + nf * 2048);       \
    } while (0)

#define MFMA16(r0q, afr, bfr)                                                   \
    do { _Pragma("unroll")                                                      \
        for (int q = 0; q < 4; ++q)                                             \
            _Pragma("unroll")                                                   \
            for (int nf = 0; nf < 4; ++nf)                                      \
                acc[(r0q) + q][nf] = __builtin_amdgcn_mfma_f32_16x16x32_bf16(   \
                    afr[q], bfr[nf], acc[(r0q) + q][nf], 0, 0, 0);              \
    } while (0)

#define PH_SYNC()                                                               \
    do { __builtin_amdgcn_s_barrier();                                          \
         asm volatile("s_waitcnt lgkmcnt(0)");                                  \
         __builtin_amdgcn_sched_barrier(0); } while (0)

#define TILE_BODY(t, bb)                                                        \
    do {                                                                        \
        /* phase a */                                                           \
        LDA(av, pA0, bb, 0);                                                    \
        LDB(bv0, pB0, bb);                                                      \
        stageA((t) + 1, 0);                                                     \
        PH_SYNC();                                                              \
        __builtin_amdgcn_s_setprio(1);  MFMA16(0, av, bv0);                     \
        __builtin_amdgcn_s_setprio(0);  __builtin_amdgcn_s_barrier();           \
        /* phase b */                                                           \
        LDA(av, pA1, bb, 0);                                                    \
        LDB(bv1, pB1, bb);                                                      \
        stageA((t) + 1, 1);                                                     \
        PH_SYNC();                                                              \
        __builtin_amdgcn_s_setprio(1);  MFMA16(0, av, bv1);                     \
        __builtin_amdgcn_s_setprio(0);  __builtin_amdgcn_s_barrier();           \
        /* phase g */                                                           \
        LDA(aw, pA0, bb, 4);                                                    \
        stageB((t) + 2, 0);                                                     \
        PH_SYNC();                                                              \
        __builtin_amdgcn_s_setprio(1);  MFMA16(4, aw, bv0);                     \
        __builtin_amdgcn_s_setprio(0);  __builtin_amdgcn_s_barrier();           \
        /* phase d */                                                           \
        LDA(aw, pA1, bb, 4);                                                    \
        stageB((t) + 2, 1);                                                     \
        PH_SYNC();                                                              \
        __builtin_amdgcn_s_setprio(1);  MFMA16(4, aw, bv1);                     \
        __builtin_amdgcn_s_setprio(0);                                          \
        asm volatile("s_waitcnt vmcnt(4)" ::: "memory");                        \
        __builtin_amdgcn_s_barrier();                                           \
    } while (0)

    // prologue: tile 0 (A+B) + tile 1 (B halves); vmcnt(4) -> tile 0 landed
    stageA(0, 0); stageA(0, 1);
    stageB(0, 0); stageB(0, 1);
    stageB(1, 0); stageB(1, 1);
    asm volatile("s_waitcnt vmcnt(4)" ::: "memory");
    __builtin_amdgcn_s_barrier();

    for (int t = 0; t < NT; t += 2) {
        TILE_BODY(t, 0);
        TILE_BODY(t + 1, 1);
    }

    // epilogue: bias + sigmoid (f/r), bf16 store
    int seg = n0 >> 10;   // block-uniform (256 | 1024)
    u16* outp = (seg == 0) ? uo : ((seg == 1) ? fo : ro);
    #pragma unroll
    for (int nf = 0; nf < 4; ++nf) {
        int col = n0 + wn * 64 + nf * 16 + lm;
        int cm = col & 1023;
        float bb2 = bias[col];
        #pragma unroll
        for (int mf = 0; mf < 8; ++mf) {
            #pragma unroll
            for (int j = 0; j < 4; ++j) {
                int row = m0 + wm * 128 + mf * 16 + lg * 4 + j;
                float val = acc[mf][nf][j] + bb2;
                if (seg != 0) val = 1.0f / (1.0f + __expf(-val));
                outp[(size_t)row * D_DIM + cm] = f2bf(val);
            }
        }
    }
#undef LDA
#undef LDB
#undef MFMA16
#undef PH_SYNC
#undef TILE_BODY
}

// ---------------- Scan phase 1 ----------------
__global__ __launch_bounds__(256) void scan1_kernel(const u16* __restrict__ fg,
                                                    const u16* __restrict__ u,
                                                    float* __restrict__ Aa,
                                                    float* __restrict__ Ss) {
    int ch = blockIdx.x;
    int bd = (blockIdx.y * 256 + threadIdx.x) * 2;
    int b = bd >> 10, d = bd & 1023;
    float a0 = 1.0f, a1 = 1.0f, s0 = 0.0f, s1 = 0.0f;
    for (int t = ch * CLEN; t < ch * CLEN + CLEN; ++t) {
        size_t idx = ((size_t)(t * B_DIM + b) << 10) + d;
        ushort2 f2 = *(const ushort2*)(fg + idx);
        ushort2 u2 = *(const ushort2*)(u + idx);
        float f0 = bf2f(f2.x), f1 = bf2f(f2.y);
        float v0 = bf2f(u2.x), v1 = bf2f(u2.y);
        s0 = f0 * s0 + (1.0f - f0) * v0;
        s1 = f1 * s1 + (1.0f - f1) * v1;
        a0 *= f0;
        a1 *= f1;
    }
    int o = ch * 8192 + bd;
    *(float2*)(Aa + o) = make_float2(a0, a1);
    *(float2*)(Ss + o) = make_float2(s0, s1);
}

// ---------------- Scan phase 2 ----------------
__global__ __launch_bounds__(256) void scan2_kernel(const float* __restrict__ Aa,
                                                    const float* __restrict__ Ss,
                                                    const float* __restrict__ c0,
                                                    float* __restrict__ cs,
                                                    float* __restrict__ lastc) {
    int bd = blockIdx.x * 256 + threadIdx.x;
    float c = c0[bd];
    #pragma unroll 4
    for (int ch = 0; ch < NCH; ++ch) {
        cs[ch * 8192 + bd] = c;
        c = Aa[ch * 8192 + bd] * c + Ss[ch * 8192 + bd];
    }
    lastc[bd] = c;
}

// ---------------- Scan phase 3: replay + recompute x_norm from x ----------------
__global__ __launch_bounds__(256) void scan3_kernel(const float* __restrict__ cs,
                                                    const u16* __restrict__ fg,
                                                    const u16* __restrict__ u,
                                                    const u16* __restrict__ rg,
                                                    const float2* __restrict__ mrs,
                                                    const float* __restrict__ gamma,
                                                    const float* __restrict__ beta,
                                                    const float* __restrict__ x,
                                                    float* __restrict__ out) {
    int ch = blockIdx.x;
    int bd = (blockIdx.y * 256 + threadIdx.x) * 2;
    int b = bd >> 10, d = bd & 1023;
    float2 gm = *(const float2*)(gamma + d);
    float2 bt = *(const float2*)(beta + d);
    float c0v = cs[ch * 8192 + bd];
    float c1v = cs[ch * 8192 + bd + 1];
    for (int t = ch * CLEN; t < ch * CLEN + CLEN; ++t) {
        size_t idx = ((size_t)(t * B_DIM + b) << 10) + d;
        ushort2 f2 = *(const ushort2*)(fg + idx);
        ushort2 u2 = *(const ushort2*)(u + idx);
        ushort2 r2 = *(const ushort2*)(rg + idx);
        float2 x2 = *(const float2*)(x + idx);
        float2 mr = mrs[t * B_DIM + b];
        float f0 = bf2f(f2.x), f1 = bf2f(f2.y);
        float v0 = bf2f(u2.x), v1 = bf2f(u2.y);
        float r0 = bf2f(r2.x), r1 = bf2f(r2.y);
        float n0 = (x2.x - mr.x) * mr.y * gm.x + bt.x;
        float n1 = (x2.y - mr.x) * mr.y * gm.y + bt.y;
        c0v = f0 * c0v + (1.0f - f0) * v0;
        c1v = f1 * c1v + (1.0f - f1) * v1;
        float h0 = r0 * tanhf(c0v) + (1.0f - r0) * n0;
        float h1 = r1 * tanhf(c1v) + (1.0f - r1) * n1;
        *(float2*)(out + idx) = make_float2(x2.x + h0, x2.y + h1);
    }
}

extern "C" void kernel_launch(void* const* d_in, const int* in_sizes, int n_in,
                              void* d_out, int out_size, void* d_ws, size_t ws_size,
                              hipStream_t stream) {
    const float* x     = (const float*)d_in[0];
    const float* c0    = (const float*)d_in[1];
    const float* W     = (const float*)d_in[2];
    const float* b     = (const float*)d_in[3];
    const float* gamma = (const float*)d_in[4];
    const float* beta  = (const float*)d_in[5];
    float* out = (float*)d_out;
    float* lastc = out + (size_t)M_DIM * D_DIM;

    char* w = (char*)d_ws;
    u16* xn = (u16*)w;  w += (size_t)M_DIM * D_DIM * 2;
    u16* Wt = (u16*)w;  w += (size_t)N_DIM * K_DIM * 2;
    u16* ug = (u16*)w;  w += (size_t)M_DIM * D_DIM * 2;
    u16* fg = (u16*)w;  w += (size_t)M_DIM * D_DIM * 2;
    u16* rg = (u16*)w;  w += (size_t)M_DIM * D_DIM * 2;
    float* Aa = (float*)w; w += (size_t)NCH * 8192 * 4;
    float* Ss = (float*)w; w += (size_t)NCH * 8192 * 4;
    float* cs = (float*)w; w += (size_t)NCH * 8192 * 4;
    float2* mrs = (float2*)w; w += (size_t)M_DIM * 8;

    hipFuncSetAttribute(reinterpret_cast<const void*>(gemm_kernel),
                        hipFuncAttributeMaxDynamicSharedMemorySize, LDS_TOTAL);

    ln_kernel<<<M_DIM, 256, 0, stream>>>(x, gamma, beta, xn, mrs);
    wt_kernel<<<dim3(K_DIM / 64, N_DIM / 64), 256, 0, stream>>>(W, Wt);
    gemm_kernel<<<dim3(M_DIM / 256, N_DIM / 256), 512, LDS_TOTAL, stream>>>(xn, Wt, b, ug, fg, rg);
    scan1_kernel<<<dim3(NCH, 16), 256, 0, stream>>>(fg, ug, Aa, Ss);
    scan2_kernel<<<32, 256, 0, stream>>>(Aa, Ss, c0, cs, lastc);
    scan3_kernel<<<dim3(NCH, 16), 256, 0, stream>>>(cs, fg, ug, rg, mrs, gamma, beta, x, out);
}

// Round 7
// 200.072 us; speedup vs baseline: 1.2152x; 1.0757x over previous
//
#include <hip/hip_runtime.h>
#include <hip/hip_bf16.h>

// SRU layer: LN -> bf16 MFMA GEMM (256^2 8-phase, balanced reads, line-ordered epilogue)
// -> chunked scan.  L=2048, B=8, D=1024, M=16384, K=1024, N=3072.

typedef unsigned short u16;
typedef __bf16 bf16x8 __attribute__((ext_vector_type(8)));
typedef float f32x4 __attribute__((ext_vector_type(4)));

#define L_DIM 2048
#define B_DIM 8
#define D_DIM 1024
#define M_DIM (L_DIM * B_DIM)   // 16384
#define K_DIM D_DIM             // 1024
#define N_DIM (3 * D_DIM)       // 3072
#define NCH 32
#define CLEN (L_DIM / NCH)      // 64
#define NT (K_DIM / 64)         // 16 K-tiles

#define LDS_B 65536
#define LDS_DUMMY 131072
#define LDS_TOTAL 147456

__device__ __forceinline__ float bf2f(u16 h) {
    unsigned int u = ((unsigned int)h) << 16;
    float f;
    __builtin_memcpy(&f, &u, 4);
    return f;
}

__device__ __forceinline__ u16 f2bf(float f) {
    unsigned int u;
    __builtin_memcpy(&u, &f, 4);
    u = u + 0x7fff + ((u >> 16) & 1);   // RNE
    return (u16)(u >> 16);
}

__device__ __forceinline__ void async16(void* lds, const void* g) {
    __builtin_amdgcn_global_load_lds(
        (const __attribute__((address_space(1))) void*)g,
        (__attribute__((address_space(3))) void*)lds, 16, 0, 0);
}

// ---------------- LayerNorm (saves per-row mu/rs for scan3) ----------------
__global__ __launch_bounds__(256) void ln_kernel(const float* __restrict__ x,
                                                 const float* __restrict__ gamma,
                                                 const float* __restrict__ beta,
                                                 u16* __restrict__ xn,
                                                 float2* __restrict__ mrs) {
    int row = blockIdx.x;
    int tid = threadIdx.x;
    const float4* xr = (const float4*)(x + (size_t)row * D_DIM);
    float4 v = xr[tid];
    float s = v.x + v.y + v.z + v.w;
    float q = v.x * v.x + v.y * v.y + v.z * v.z + v.w * v.w;
    #pragma unroll
    for (int off = 32; off; off >>= 1) {
        s += __shfl_down(s, off);
        q += __shfl_down(q, off);
    }
    __shared__ float ss[4], qq[4];
    int lane = tid & 63, wv = tid >> 6;
    if (lane == 0) { ss[wv] = s; qq[wv] = q; }
    __syncthreads();
    s = ss[0] + ss[1] + ss[2] + ss[3];
    q = qq[0] + qq[1] + qq[2] + qq[3];
    float mu = s * (1.0f / D_DIM);
    float var = q * (1.0f / D_DIM) - mu * mu;
    float rs = rsqrtf(var + 1e-5f);
    if (tid == 0) mrs[row] = make_float2(mu, rs);
    float4 g = ((const float4*)gamma)[tid];
    float4 bt = ((const float4*)beta)[tid];
    ushort4 o;
    o.x = f2bf((v.x - mu) * rs * g.x + bt.x);
    o.y = f2bf((v.y - mu) * rs * g.y + bt.y);
    o.z = f2bf((v.z - mu) * rs * g.z + bt.z);
    o.w = f2bf((v.w - mu) * rs * g.w + bt.w);
    ((ushort4*)(xn + (size_t)row * D_DIM))[tid] = o;
}

// ---------------- W transpose+convert: W[K][N] f32 -> Wt[N][K] bf16 ----------------
__global__ __launch_bounds__(256) void wt_kernel(const float* __restrict__ W,
                                                 u16* __restrict__ Wt) {
    __shared__ float t[64][65];
    int k0 = blockIdx.x * 64;
    int n0 = blockIdx.y * 64;
    int col = threadIdx.x & 63;
    int rg4 = threadIdx.x >> 6;
    #pragma unroll
    for (int j = 0; j < 16; ++j) {
        int r = rg4 * 16 + j;
        t[r][col] = W[(size_t)(k0 + r) * N_DIM + n0 + col];
    }
    __syncthreads();
    #pragma unroll
    for (int j = 0; j < 16; ++j) {
        int nr = rg4 * 16 + j;
        Wt[(size_t)(n0 + nr) * K_DIM + k0 + col] = f2bf(t[col][nr]);
    }
}

// ---------------- GEMM: 256x256, BK=64, 8 waves, 8-phase, balanced reads ----------------
// Phases (ds_read bytes 64/64/32/32 KB):
//   phase a: {av kk0, bv0}  stage A(t+1)h0   MFMA(mf0-3, kk0)
//   phase b: {av kk1, bv1}  stage A(t+1)h1   MFMA(mf0-3, kk1)
//   phase g: {aw kk0}       stage B(t+2)h0   MFMA(mf4-7, kk0)
//   phase d: {aw kk1}       stage B(t+2)h1   MFMA(mf4-7, kk1); vmcnt(4)
// Race proof as R2. Epilogue stores complete 64B lines back-to-back (nf innermost).
__global__ __launch_bounds__(512, 2) void gemm_kernel(const u16* __restrict__ A,
                                                      const u16* __restrict__ Bt,
                                                      const float* __restrict__ bias,
                                                      u16* __restrict__ uo,
                                                      u16* __restrict__ fo,
                                                      u16* __restrict__ ro) {
    extern __shared__ char lds[];
    const int tid = threadIdx.x;
    const int wave = tid >> 6, lane = tid & 63;
    const int lm = lane & 15, lg = lane >> 4;
    const int wm = wave >> 2, wn = wave & 3;   // 2M x 4N waves
    const int m0 = blockIdx.x * 256;           // natural grid (L2 locality)
    const int n0 = blockIdx.y * 256;

    // --- precomputed ds_read bases ---
    const int xk0 = ((0 | lg) ^ (lm & 7)) << 4;
    const int xk1 = ((4 | lg) ^ (lm & 7)) << 4;
    const char* pA0 = lds + (wm * 128 + lm) * 128 + xk0;
    const char* pA1 = lds + (wm * 128 + lm) * 128 + xk1;
    const char* pB0 = lds + LDS_B + (wn * 64 + lm) * 128 + xk0;
    const char* pB1 = lds + LDS_B + (wn * 64 + lm) * 128 + xk1;

    // --- precomputed staging addresses ---
    const int c1 = 512 + tid;
    const int r0 = tid >> 3, cc0 = (tid & 7) ^ (r0 & 7);   // pre-swizzled src (rule 21)
    const int r1 = c1 >> 3, cc1 = (c1 & 7) ^ (r1 & 7);
    const char* gA0 = (const char*)A + ((size_t)(m0 + r0) * K_DIM + cc0 * 8) * 2;
    const char* gA1 = (const char*)A + ((size_t)(m0 + r1) * K_DIM + cc1 * 8) * 2;
    const char* gB0 = (const char*)Bt + ((size_t)(n0 + r0) * K_DIM + cc0 * 8) * 2;
    const char* gB1 = (const char*)Bt + ((size_t)(n0 + r1) * K_DIM + cc1 * 8) * 2;
    char* dstW = lds + wave * 1024;

    f32x4 acc[8][4] = {};
    bf16x8 av[4], aw[4], bv0[4], bv1[4];

    auto stageA = [&](int t1, int h) {
        char* dst = (t1 < NT) ? (dstW + ((t1 & 1) << 15) + (h << 14))
                              : (lds + LDS_DUMMY + wave * 1024);
        int ko = ((t1 & 15) << 7) + (h << 18);
        async16(dst,        gA0 + ko);
        async16(dst + 8192, gA1 + ko);
    };
    auto stageB = [&](int t2, int h) {
        char* dst = (t2 < NT) ? (dstW + LDS_B + ((t2 & 1) << 15) + (h << 14))
                              : (lds + LDS_DUMMY + wave * 1024);
        int ko = ((t2 & 15) << 7) + (h << 18);
        async16(dst,        gB0 + ko);
        async16(dst + 8192, gB1 + ko);
    };

#define LDA(dst, pbase, bb, mf0)                                                \
    do { _Pragma("unroll")                                                      \
        for (int q = 0; q < 4; ++q)                                             \
            dst[q] = *(const bf16x8*)(pbase + (bb) * 32768 + ((mf0) + q) * 2048); \
    } while (0)

#define LDB(dst, pbase, bb)                                                     \
    do { _Pragma("unroll")                                                      \
        for (int nf = 0; nf < 4; ++nf)                                          \
            dst[nf] = *(const bf16x8*)(pbase + (bb) * 32768 + nf * 2048);       \
    } while (0)

#define MFMA16(r0q, afr, bfr)                                                   \
    do { _Pragma("unroll")                                                      \
        for (int q = 0; q < 4; ++q)                                             \
            _Pragma("unroll")                                                   \
            for (int nf = 0; nf < 4; ++nf)                                      \
                acc[(r0q) + q][nf] = __builtin_amdgcn_mfma_f32_16x16x32_bf16(   \
                    afr[q], bfr[nf], acc[(r0q) + q][nf], 0, 0, 0);              \
    } while (0)

#define PH_SYNC()                                                               \
    do { __builtin_amdgcn_s_barrier();                                          \
         asm volatile("s_waitcnt lgkmcnt(0)");                                  \
         __builtin_amdgcn_sched_barrier(0); } while (0)

#define TILE_BODY(t, bb)                                                        \
    do {                                                                        \
        /* phase a */                                                           \
        LDA(av, pA0, bb, 0);                                                    \
        LDB(bv0, pB0, bb);                                                      \
        stageA((t) + 1, 0);                                                     \
        PH_SYNC();                                                              \
        __builtin_amdgcn_s_setprio(1);  MFMA16(0, av, bv0);                     \
        __builtin_amdgcn_s_setprio(0);  __builtin_amdgcn_s_barrier();           \
        /* phase b */                                                           \
        LDA(av, pA1, bb, 0);                                                    \
        LDB(bv1, pB1, bb);                                                      \
        stageA((t) + 1, 1);                                                     \
        PH_SYNC();                                                              \
        __builtin_amdgcn_s_setprio(1);  MFMA16(0, av, bv1);                     \
        __builtin_amdgcn_s_setprio(0);  __builtin_amdgcn_s_barrier();           \
        /* phase g */                                                           \
        LDA(aw, pA0, bb, 4);                                                    \
        stageB((t) + 2, 0);                                                     \
        PH_SYNC();                                                              \
        __builtin_amdgcn_s_setprio(1);  MFMA16(4, aw, bv0);                     \
        __builtin_amdgcn_s_setprio(0);  __builtin_amdgcn_s_barrier();           \
        /* phase d */                                                           \
        LDA(aw, pA1, bb, 4);                                                    \
        stageB((t) + 2, 1);                                                     \
        PH_SYNC();                                                              \
        __builtin_amdgcn_s_setprio(1);  MFMA16(4, aw, bv1);                     \
        __builtin_amdgcn_s_setprio(0);                                          \
        asm volatile("s_waitcnt vmcnt(4)" ::: "memory");                        \
        __builtin_amdgcn_s_barrier();                                           \
    } while (0)

    // prologue: tile 0 (A+B) + tile 1 (B halves); vmcnt(4) -> tile 0 landed
    stageA(0, 0); stageA(0, 1);
    stageB(0, 0); stageB(0, 1);
    stageB(1, 0); stageB(1, 1);
    asm volatile("s_waitcnt vmcnt(4)" ::: "memory");
    __builtin_amdgcn_s_barrier();

    for (int t = 0; t < NT; t += 2) {
        TILE_BODY(t, 0);
        TILE_BODY(t + 1, 1);
    }

    // epilogue: bias + sigmoid (f/r), bf16 store.
    // nf INNERMOST: 4 consecutive stores per row span cols 0..63 (two complete
    // 64B lines back-to-back) -> no partial-line write amplification (R6 lesson).
    int seg = n0 >> 10;   // block-uniform (256 | 1024)
    u16* outp = (seg == 0) ? uo : ((seg == 1) ? fo : ro);
    float bb4[4];
    #pragma unroll
    for (int nf = 0; nf < 4; ++nf) bb4[nf] = bias[n0 + wn * 64 + nf * 16 + lm];
    const int cmb = (n0 + wn * 64 + lm) & 1023;
    #pragma unroll
    for (int mf = 0; mf < 8; ++mf) {
        #pragma unroll
        for (int j = 0; j < 4; ++j) {
            int row = m0 + wm * 128 + mf * 16 + lg * 4 + j;
            u16* rp = outp + (size_t)row * D_DIM + cmb;
            #pragma unroll
            for (int nf = 0; nf < 4; ++nf) {
                float val = acc[mf][nf][j] + bb4[nf];
                if (seg != 0) val = 1.0f / (1.0f + __expf(-val));
                rp[nf * 16] = f2bf(val);
            }
        }
    }
#undef LDA
#undef LDB
#undef MFMA16
#undef PH_SYNC
#undef TILE_BODY
}

// ---------------- Scan phase 1 ----------------
__global__ __launch_bounds__(256) void scan1_kernel(const u16* __restrict__ fg,
                                                    const u16* __restrict__ u,
                                                    float* __restrict__ Aa,
                                                    float* __restrict__ Ss) {
    int ch = blockIdx.x;
    int bd = (blockIdx.y * 256 + threadIdx.x) * 2;
    int b = bd >> 10, d = bd & 1023;
    float a0 = 1.0f, a1 = 1.0f, s0 = 0.0f, s1 = 0.0f;
    for (int t = ch * CLEN; t < ch * CLEN + CLEN; ++t) {
        size_t idx = ((size_t)(t * B_DIM + b) << 10) + d;
        ushort2 f2 = *(const ushort2*)(fg + idx);
        ushort2 u2 = *(const ushort2*)(u + idx);
        float f0 = bf2f(f2.x), f1 = bf2f(f2.y);
        float v0 = bf2f(u2.x), v1 = bf2f(u2.y);
        s0 = f0 * s0 + (1.0f - f0) * v0;
        s1 = f1 * s1 + (1.0f - f1) * v1;
        a0 *= f0;
        a1 *= f1;
    }
    int o = ch * 8192 + bd;
    *(float2*)(Aa + o) = make_float2(a0, a1);
    *(float2*)(Ss + o) = make_float2(s0, s1);
}

// ---------------- Scan phase 2 ----------------
__global__ __launch_bounds__(256) void scan2_kernel(const float* __restrict__ Aa,
                                                    const float* __restrict__ Ss,
                                                    const float* __restrict__ c0,
                                                    float* __restrict__ cs,
                                                    float* __restrict__ lastc) {
    int bd = blockIdx.x * 256 + threadIdx.x;
    float c = c0[bd];
    #pragma unroll 4
    for (int ch = 0; ch < NCH; ++ch) {
        cs[ch * 8192 + bd] = c;
        c = Aa[ch * 8192 + bd] * c + Ss[ch * 8192 + bd];
    }
    lastc[bd] = c;
}

// ---------------- Scan phase 3: replay + recompute x_norm from x ----------------
__global__ __launch_bounds__(256) void scan3_kernel(const float* __restrict__ cs,
                                                    const u16* __restrict__ fg,
                                                    const u16* __restrict__ u,
                                                    const u16* __restrict__ rg,
                                                    const float2* __restrict__ mrs,
                                                    const float* __restrict__ gamma,
                                                    const float* __restrict__ beta,
                                                    const float* __restrict__ x,
                                                    float* __restrict__ out) {
    int ch = blockIdx.x;
    int bd = (blockIdx.y * 256 + threadIdx.x) * 2;
    int b = bd >> 10, d = bd & 1023;
    float2 gm = *(const float2*)(gamma + d);
    float2 bt = *(const float2*)(beta + d);
    float c0v = cs[ch * 8192 + bd];
    float c1v = cs[ch * 8192 + bd + 1];
    for (int t = ch * CLEN; t < ch * CLEN + CLEN; ++t) {
        size_t idx = ((size_t)(t * B_DIM + b) << 10) + d;
        ushort2 f2 = *(const ushort2*)(fg + idx);
        ushort2 u2 = *(const ushort2*)(u + idx);
        ushort2 r2 = *(const ushort2*)(rg + idx);
        float2 x2 = *(const float2*)(x + idx);
        float2 mr = mrs[t * B_DIM + b];
        float f0 = bf2f(f2.x), f1 = bf2f(f2.y);
        float v0 = bf2f(u2.x), v1 = bf2f(u2.y);
        float r0 = bf2f(r2.x), r1 = bf2f(r2.y);
        float n0 = (x2.x - mr.x) * mr.y * gm.x + bt.x;
        float n1 = (x2.y - mr.x) * mr.y * gm.y + bt.y;
        c0v = f0 * c0v + (1.0f - f0) * v0;
        c1v = f1 * c1v + (1.0f - f1) * v1;
        float h0 = r0 * tanhf(c0v) + (1.0f - r0) * n0;
        float h1 = r1 * tanhf(c1v) + (1.0f - r1) * n1;
        *(float2*)(out + idx) = make_float2(x2.x + h0, x2.y + h1);
    }
}

extern "C" void kernel_launch(void* const* d_in, const int* in_sizes, int n_in,
                              void* d_out, int out_size, void* d_ws, size_t ws_size,
                              hipStream_t stream) {
    const float* x     = (const float*)d_in[0];
    const float* c0    = (const float*)d_in[1];
    const float* W     = (const float*)d_in[2];
    const float* b     = (const float*)d_in[3];
    const float* gamma = (const float*)d_in[4];
    const float* beta  = (const float*)d_in[5];
    float* out = (float*)d_out;
    float* lastc = out + (size_t)M_DIM * D_DIM;

    char* w = (char*)d_ws;
    u16* xn = (u16*)w;  w += (size_t)M_DIM * D_DIM * 2;
    u16* Wt = (u16*)w;  w += (size_t)N_DIM * K_DIM * 2;
    u16* ug = (u16*)w;  w += (size_t)M_DIM * D_DIM * 2;
    u16* fg = (u16*)w;  w += (size_t)M_DIM * D_DIM * 2;
    u16* rg = (u16*)w;  w += (size_t)M_DIM * D_DIM * 2;
    float* Aa = (float*)w; w += (size_t)NCH * 8192 * 4;
    float* Ss = (float*)w; w += (size_t)NCH * 8192 * 4;
    float* cs = (float*)w; w += (size_t)NCH * 8192 * 4;
    float2* mrs = (float2*)w; w += (size_t)M_DIM * 8;

    hipFuncSetAttribute(reinterpret_cast<const void*>(gemm_kernel),
                        hipFuncAttributeMaxDynamicSharedMemorySize, LDS_TOTAL);

    ln_kernel<<<M_DIM, 256, 0, stream>>>(x, gamma, beta, xn, mrs);
    wt_kernel<<<dim3(K_DIM / 64, N_DIM / 64), 256, 0, stream>>>(W, Wt);
    gemm_kernel<<<dim3(M_DIM / 256, N_DIM / 256), 512, LDS_TOTAL, stream>>>(xn, Wt, b, ug, fg, rg);
    scan1_kernel<<<dim3(NCH, 16), 256, 0, stream>>>(fg, ug, Aa, Ss);
    scan2_kernel<<<32, 256, 0, stream>>>(Aa, Ss, c0, cs, lastc);
    scan3_kernel<<<dim3(NCH, 16), 256, 0, stream>>>(cs, fg, ug, rg, mrs, gamma, beta, x, out);
}